// Round 1
// baseline (326.157 us; speedup 1.0000x reference)
//
#include <hip/hip_runtime.h>
#include <math.h>

#define BS   64
#define CH   256
#define NPIX 3136        // 56*56
#define NK   3
#define TILE 512         // pixels per block (2 per thread in phase A)
#define TPB  256
#define TILES_PER_IMG 7  // ceil(3136/512); last tile has 64 px

#define QX_ELEMS (BS*NK*CH)  // 49152
#define SA_ELEMS (BS*NK)     // 192

// ---------------------------------------------------------------------------
// Kernel 1: per-pixel soft assignment (softmax over 3 parts) + weighted-pool
// partial accumulation into qx[b][k][c] (global atomics) and sum_ass[b][k].
// ---------------------------------------------------------------------------
__global__ __launch_bounds__(TPB)
void pgn_assign(const float* __restrict__ x,        // [BS][CH][NPIX]
                const float* __restrict__ centers,  // [NK][CH]
                const float* __restrict__ psf,      // [NK]
                float* __restrict__ assign_out,     // [BS][NK][NPIX]
                float* __restrict__ qx,             // [BS][NK][CH]  (pre-zeroed)
                float* __restrict__ sa)             // [BS][NK]      (pre-zeroed)
{
    __shared__ float4 ctr4[CH];        // {c0,c1,c2,0} per channel, 4 KB
    __shared__ float  a_sh[NK][TILE];  // assign stash for phase B, 6 KB
    __shared__ float  csq_sh[NK];
    __shared__ float  sa_sh[NK];

    const int tid = threadIdx.x;
    const int bid = blockIdx.x;
    const int b   = bid / TILES_PER_IMG;
    const int t   = bid % TILES_PER_IMG;
    const int n0  = t * TILE + tid * 2;      // first of this thread's 2 pixels
    const bool valid = (n0 < NPIX);

    // ---- centers -> LDS ----
    {
        const float c0 = centers[0*CH + tid];
        const float c1 = centers[1*CH + tid];
        const float c2 = centers[2*CH + tid];
        ctr4[tid] = make_float4(c0, c1, c2, 0.f);
        if (tid < NK) sa_sh[tid] = 0.f;
    }
    __syncthreads();
    if (tid < NK) {  // c_sq[k] = sum_c centers[k][c]^2  (once per block, hidden)
        const float* cf = (const float*)ctr4;
        float s = 0.f;
        #pragma unroll 8
        for (int c = 0; c < CH; ++c) { const float u = cf[4*c + tid]; s = fmaf(u, u, s); }
        csq_sh[tid] = s;
    }
    __syncthreads();

    // rbeta = 1/sigmoid(psf) = 1 + exp(-psf)
    const float rb0 = 1.f + __expf(-psf[0]);
    const float rb1 = 1.f + __expf(-psf[1]);
    const float rb2 = 1.f + __expf(-psf[2]);
    const float cs0 = csq_sh[0], cs1 = csq_sh[1], cs2 = csq_sh[2];

    // ---- Phase A: coalesced dot products + softmax over k ----
    float a00=0.f,a01=0.f,a10=0.f,a11=0.f,a20=0.f,a21=0.f;
    if (valid) {
        const float* xb = x + (size_t)b * CH * NPIX + n0;
        float cx00=0.f,cx01=0.f,cx10=0.f,cx11=0.f,cx20=0.f,cx21=0.f,xs0=0.f,xs1=0.f;
        #pragma unroll 4
        for (int c = 0; c < CH; ++c) {
            const float2 xv = *(const float2*)(xb + (size_t)c * NPIX);
            const float4 cc = ctr4[c];
            cx00 = fmaf(cc.x, xv.x, cx00); cx01 = fmaf(cc.x, xv.y, cx01);
            cx10 = fmaf(cc.y, xv.x, cx10); cx11 = fmaf(cc.y, xv.y, cx11);
            cx20 = fmaf(cc.z, xv.x, cx20); cx21 = fmaf(cc.z, xv.y, cx21);
            xs0  = fmaf(xv.x, xv.x, xs0);  xs1  = fmaf(xv.y, xv.y, xs1);
        }
        // pixel 0
        {
            const float l0 = fminf(2.f*cx00 - xs0 - cs0, 0.f) * rb0;
            const float l1 = fminf(2.f*cx10 - xs0 - cs1, 0.f) * rb1;
            const float l2 = fminf(2.f*cx20 - xs0 - cs2, 0.f) * rb2;
            const float m  = fmaxf(l0, fmaxf(l1, l2));
            const float e0 = __expf(l0 - m), e1 = __expf(l1 - m), e2 = __expf(l2 - m);
            const float inv = 1.f / (e0 + e1 + e2);
            a00 = e0*inv; a10 = e1*inv; a20 = e2*inv;
        }
        // pixel 1
        {
            const float l0 = fminf(2.f*cx01 - xs1 - cs0, 0.f) * rb0;
            const float l1 = fminf(2.f*cx11 - xs1 - cs1, 0.f) * rb1;
            const float l2 = fminf(2.f*cx21 - xs1 - cs2, 0.f) * rb2;
            const float m  = fmaxf(l0, fmaxf(l1, l2));
            const float e0 = __expf(l0 - m), e1 = __expf(l1 - m), e2 = __expf(l2 - m);
            const float inv = 1.f / (e0 + e1 + e2);
            a01 = e0*inv; a11 = e1*inv; a21 = e2*inv;
        }
        // write assign output (coalesced float2 per k)
        float* ao = assign_out + (size_t)b * NK * NPIX + n0;
        *(float2*)(ao)            = make_float2(a00, a01);
        *(float2*)(ao + NPIX)     = make_float2(a10, a11);
        *(float2*)(ao + 2*NPIX)   = make_float2(a20, a21);
    }
    // stash assign in LDS (zeros for invalid threads so phase B is clean)
    a_sh[0][tid*2] = a00; a_sh[0][tid*2+1] = a01;
    a_sh[1][tid*2] = a10; a_sh[1][tid*2+1] = a11;
    a_sh[2][tid*2] = a20; a_sh[2][tid*2+1] = a21;
    // per-block sum of assignments
    const float s0 = a00 + a01, s1 = a10 + a11, s2 = a20 + a21;
    if (valid) {
        atomicAdd(&sa_sh[0], s0);
        atomicAdd(&sa_sh[1], s1);
        atomicAdd(&sa_sh[2], s2);
    }
    __syncthreads();

    // ---- Phase B: lane = channel; per-lane sequential row reads (L2/L3 hot),
    //      assign from LDS broadcast; zero cross-lane ops. ----
    const int nbase  = t * TILE;
    const int nvalid = (NPIX - nbase < TILE) ? (NPIX - nbase) : TILE;
    const float* xr  = x + ((size_t)b * CH + tid) * NPIX + nbase;
    float q0 = 0.f, q1 = 0.f, q2 = 0.f;
    #pragma unroll 8
    for (int p = 0; p < nvalid; p += 4) {
        const float4 xv = *(const float4*)(xr + p);
        const float4 A0 = *(const float4*)&a_sh[0][p];
        const float4 A1 = *(const float4*)&a_sh[1][p];
        const float4 A2 = *(const float4*)&a_sh[2][p];
        q0 = fmaf(A0.x, xv.x, fmaf(A0.y, xv.y, fmaf(A0.z, xv.z, fmaf(A0.w, xv.w, q0))));
        q1 = fmaf(A1.x, xv.x, fmaf(A1.y, xv.y, fmaf(A1.z, xv.z, fmaf(A1.w, xv.w, q1))));
        q2 = fmaf(A2.x, xv.x, fmaf(A2.y, xv.y, fmaf(A2.z, xv.z, fmaf(A2.w, xv.w, q2))));
    }
    float* qb = qx + (size_t)b * NK * CH + tid;
    atomicAdd(qb,          q0);
    atomicAdd(qb + CH,     q1);
    atomicAdd(qb + 2*CH,   q2);

    if (tid < NK) atomicAdd(&sa[b*NK + tid], sa_sh[tid]);
}

// ---------------------------------------------------------------------------
// Kernel 2: finalize — qx/sum_ass, subtract centers, /sigma, L2-normalize
// over channels, transposed store to outputs[b][c][k].
// ---------------------------------------------------------------------------
__global__ __launch_bounds__(TPB)
void pgn_final(const float* __restrict__ qx,       // [BS][NK][CH]
               const float* __restrict__ sa,       // [BS][NK]
               const float* __restrict__ centers,  // [NK][CH]
               const float* __restrict__ psf,      // [NK]
               float* __restrict__ out)            // [BS][CH][NK]
{
    const int b = blockIdx.x;
    const int c = threadIdx.x;
    const int wave = c >> 6, lane = c & 63;
    __shared__ float red[4][NK];
    __shared__ float nrm[NK];

    float v[NK];
    float ss[NK];
    #pragma unroll
    for (int k = 0; k < NK; ++k) {
        const float beta = 1.f / (1.f + __expf(-psf[k]));
        const float sig  = sqrtf(0.5f * beta);
        const float s    = fmaxf(sa[b*NK + k], 1e-5f);
        const float q    = qx[((size_t)b*NK + k)*CH + c] / s;
        v[k]  = (q - centers[k*CH + c]) / sig;
        ss[k] = v[k] * v[k];
    }
    // wave reduce the 3 sums of squares
    #pragma unroll
    for (int m = 32; m; m >>= 1) {
        ss[0] += __shfl_xor(ss[0], m, 64);
        ss[1] += __shfl_xor(ss[1], m, 64);
        ss[2] += __shfl_xor(ss[2], m, 64);
    }
    if (lane == 0) { red[wave][0] = ss[0]; red[wave][1] = ss[1]; red[wave][2] = ss[2]; }
    __syncthreads();
    if (c < NK) {
        const float tot = red[0][c] + red[1][c] + red[2][c] + red[3][c];
        nrm[c] = fmaxf(sqrtf(tot), 1e-12f);
    }
    __syncthreads();
    float* o = out + ((size_t)b*CH + c)*NK;
    #pragma unroll
    for (int k = 0; k < NK; ++k) o[k] = v[k] / nrm[k];
}

// ---------------------------------------------------------------------------
extern "C" void kernel_launch(void* const* d_in, const int* in_sizes, int n_in,
                              void* d_out, int out_size, void* d_ws, size_t ws_size,
                              hipStream_t stream)
{
    const float* feat    = (const float*)d_in[0];
    const float* centers = (const float*)d_in[1];
    const float* psf     = (const float*)d_in[2];

    float* out        = (float*)d_out;                 // [BS][CH][NK] first
    float* assign_out = out + (size_t)BS*CH*NK;        // then [BS][NK][NPIX]

    float* qx = (float*)d_ws;                          // [BS][NK][CH]
    float* sa = qx + QX_ELEMS;                         // [BS][NK]

    hipMemsetAsync(d_ws, 0, (QX_ELEMS + SA_ELEMS) * sizeof(float), stream);

    pgn_assign<<<dim3(BS * TILES_PER_IMG), dim3(TPB), 0, stream>>>(
        feat, centers, psf, assign_out, qx, sa);

    pgn_final<<<dim3(BS), dim3(TPB), 0, stream>>>(qx, sa, centers, psf, out);
}